// Round 2
// baseline (1188.596 us; speedup 1.0000x reference)
//
#include <hip/hip_runtime.h>
#include <math.h>

// MoE: T=8192 D=1024 H=4096 E=8 top_k=2.
// Pipeline: router -> count -> scan -> scatter -> split x -> transpose+split W1/W2
//           -> grouped up-GEMM (gelu*gate, write h planes) -> grouped down-GEMM -> combine.
// GEMMs: split-bf16 (hi/lo) MFMA 16x16x32, 3 products per MAC for ~fp32 accuracy.
// BK=32 LDS rows (64B); global_load_lds width-16 staging (m97 structure).

#define T_TOK 8192
#define DDIM 1024
#define HDIM 4096
#define NEXP 8
#define BM 128
#define BN 128
#define BK 32
#define R_MAX (T_TOK * 2)
#define R_PAD (R_MAX + NEXP * BM)          // 17408
#define ROWTILES ((R_MAX / BM) + NEXP)     // 136

typedef unsigned short u16;
typedef unsigned int u32;
typedef __attribute__((ext_vector_type(4))) float f32x4;
typedef __attribute__((ext_vector_type(8))) short bf16x8;

__device__ __forceinline__ u16 f2bf(float f) {
  union { float f; u32 u; } v; v.f = f;
  u32 r = v.u + 0x7fffu + ((v.u >> 16) & 1u);   // round-to-nearest-even
  return (u16)(r >> 16);
}
__device__ __forceinline__ float bf2f(u16 h) {
  union { u32 u; float f; } v; v.u = ((u32)h) << 16; return v.f;
}
__device__ __forceinline__ void gll16(const void* g, void* l) {
  __builtin_amdgcn_global_load_lds(
      (const __attribute__((address_space(1))) u32*)g,
      (__attribute__((address_space(3))) u32*)l, 16, 0, 0);
}

// ---------------- router: logits (exact fp32, to d_out), top-2 sel + weights ----------------
__global__ __launch_bounds__(256) void k_router(const float* __restrict__ x,
                                                const float* __restrict__ Wg,
                                                float* __restrict__ logits,
                                                int* __restrict__ sel,
                                                float* __restrict__ wts) {
  __shared__ float wg[NEXP * DDIM];
  const int t = threadIdx.x;
  for (int i = t; i < NEXP * DDIM; i += 256) wg[i] = Wg[i];
  __syncthreads();
  const int wave = t >> 6, lane = t & 63;
  const int tok = blockIdx.x * 4 + wave;            // grid = T/4
  const float* xr = x + (size_t)tok * DDIM;
  float acc[NEXP];
#pragma unroll
  for (int e = 0; e < NEXP; ++e) acc[e] = 0.f;
  for (int c = 0; c < DDIM / 64; ++c) {
    const float xv = xr[c * 64 + lane];
#pragma unroll
    for (int e = 0; e < NEXP; ++e) acc[e] += xv * wg[e * DDIM + c * 64 + lane];
  }
#pragma unroll
  for (int e = 0; e < NEXP; ++e) {
    float v = acc[e];
    for (int off = 32; off; off >>= 1) v += __shfl_xor(v, off, 64);
    acc[e] = v;
  }
  if (lane < NEXP) logits[(size_t)tok * NEXP + lane] = acc[lane];
  if (lane == 0) {
    int i1 = 0; float m1 = acc[0];
#pragma unroll
    for (int e = 1; e < NEXP; ++e) if (acc[e] > m1) { m1 = acc[e]; i1 = e; }
    int i2 = -1; float m2 = -INFINITY;
#pragma unroll
    for (int e = 0; e < NEXP; ++e) if (e != i1 && acc[e] > m2) { m2 = acc[e]; i2 = e; }
    const float ex = expf(m2 - m1);          // == p2/p1; renorm top-2 softmax
    const float w1 = 1.f / (1.f + ex);
    sel[tok * 2 + 0] = i1; sel[tok * 2 + 1] = i2;
    wts[tok * 2 + 0] = w1; wts[tok * 2 + 1] = ex * w1;
  }
}

// ---------------- per-expert counts (wave-aggregated atomics) ----------------
__global__ __launch_bounds__(256) void k_count(const int* __restrict__ sel, int* __restrict__ cnt) {
  const int t = blockIdx.x * 256 + threadIdx.x;     // grid 32 -> 8192 tokens
  const int lane = threadIdx.x & 63;
  for (int k = 0; k < 2; ++k) {
    const int s = sel[t * 2 + k];
#pragma unroll
    for (int e = 0; e < NEXP; ++e) {
      const unsigned long long m = __ballot(s == e);
      if (m && lane == __builtin_ctzll(m)) atomicAdd(&cnt[e], __popcll(m));
    }
  }
}

// ---------------- padded prefix offsets ----------------
__global__ void k_scan(const int* __restrict__ cnt, int* __restrict__ poff) {
  if (threadIdx.x == 0 && blockIdx.x == 0) {
    int run = 0;
    for (int e = 0; e < NEXP; ++e) { poff[e] = run; run += ((cnt[e] + BM - 1) / BM) * BM; }
    poff[NEXP] = run;
  }
}

// ---------------- scatter tokens into per-expert segments ----------------
__global__ __launch_bounds__(256) void k_scatter(const int* __restrict__ sel,
                                                 const float* __restrict__ wts,
                                                 const int* __restrict__ poff,
                                                 int* __restrict__ cursor,
                                                 int* __restrict__ rows,
                                                 float* __restrict__ gw,
                                                 int* __restrict__ posof) {
  const int t = blockIdx.x * 256 + threadIdx.x;
  const int lane = threadIdx.x & 63;
  for (int k = 0; k < 2; ++k) {
    const int s = sel[t * 2 + k];
    const float w = wts[t * 2 + k];
#pragma unroll
    for (int e = 0; e < NEXP; ++e) {
      const unsigned long long m = __ballot(s == e);
      if (!m) continue;
      const int leader = __builtin_ctzll(m);
      int base = 0;
      if (lane == leader) base = atomicAdd(&cursor[e], (int)__popcll(m));
      base = __shfl(base, leader, 64);
      if (s == e) {
        const int pos = base + (int)__popcll(m & ((1ull << lane) - 1ull));
        const int g = poff[e] + pos;
        rows[g] = t; gw[g] = w; posof[t * 2 + k] = g;
      }
    }
  }
}

// ---------------- split x fp32 -> bf16 hi (+optional lo) planes ----------------
__global__ __launch_bounds__(256) void k_splitx(const float* __restrict__ x,
                                                u16* __restrict__ xhi, u16* __restrict__ xlo,
                                                int wlo) {
  const size_t i = (size_t)blockIdx.x * 256 + threadIdx.x;   // over T*D/4
  const float4 v = ((const float4*)x)[i];
  float vv[4] = {v.x, v.y, v.z, v.w};
  u16 h[4], l[4];
#pragma unroll
  for (int j = 0; j < 4; ++j) { h[j] = f2bf(vv[j]); l[j] = f2bf(vv[j] - bf2f(h[j])); }
  ((ushort4*)xhi)[i] = make_ushort4(h[0], h[1], h[2], h[3]);
  if (wlo) ((ushort4*)xlo)[i] = make_ushort4(l[0], l[1], l[2], l[3]);
}

// ---------------- transpose + split weights: in [E][Rr][Cc] fp32 -> out [E][Cc][Rr] bf16 ----------------
__global__ __launch_bounds__(256) void k_tsplit(const float* __restrict__ in,
                                                u16* __restrict__ ohi, u16* __restrict__ olo,
                                                int Rr, int Cc, int wlo) {
  __shared__ float tile[64][65];
  const int tilesC = Cc / 64;
  const int per = (Rr / 64) * tilesC;
  const int e = blockIdx.x / per, rem = blockIdx.x % per;
  const int rt = rem / tilesC, ct = rem % tilesC;
  const float* bin = in + ((size_t)e * Rr + rt * 64) * Cc + ct * 64;
  const int r0 = threadIdx.x >> 6, c = threadIdx.x & 63;
#pragma unroll
  for (int i = 0; i < 16; ++i) tile[i * 4 + r0][c] = bin[(size_t)(i * 4 + r0) * Cc + c];
  __syncthreads();
  u16* bhi = ohi + ((size_t)e * Cc + ct * 64) * Rr + rt * 64;
  u16* blo = wlo ? olo + ((size_t)e * Cc + ct * 64) * Rr + rt * 64 : nullptr;
#pragma unroll
  for (int i = 0; i < 16; ++i) {
    const int orow = i * 4 + r0;
    const float v = tile[c][orow];            // (c + orow) % 32 -> 2 lanes/bank, free
    const u16 h = f2bf(v);
    bhi[(size_t)orow * Rr + c] = h;
    if (wlo) blo[(size_t)orow * Rr + c] = f2bf(v - bf2f(h));
  }
}

// ---------------- grouped GEMM (up: gather x rows, gelu*gate -> h planes; down: h rows -> ydown) ----------------
template <bool IS_UP, bool ALO, bool BLO, bool WLO>
__global__ __launch_bounds__(256, 2) void k_gemm(
    const u16* __restrict__ Ahi, const u16* __restrict__ Alo,
    const u16* __restrict__ Bhi, const u16* __restrict__ Blo,
    const int* __restrict__ poff, const int* __restrict__ cnt,
    const int* __restrict__ rows, const float* __restrict__ gw,
    u16* __restrict__ OHi, u16* __restrict__ OLo, float* __restrict__ OF) {
  constexpr int KD = IS_UP ? DDIM : HDIM;
  constexpr int ND = IS_UP ? HDIM : DDIM;
  constexpr int NT = ND / BN;
  const int rt = blockIdx.x / NT, ct = blockIdx.x % NT;
  const int r0 = rt * BM;
  if (r0 >= poff[NEXP]) return;
  int e = 0;
#pragma unroll
  for (int i = 1; i < NEXP; ++i) if (r0 >= poff[i]) e = i;
  const int lim = poff[e] + cnt[e];
  const int n0 = ct * BN;

  __shared__ __align__(16) u16 sA[2][BM * BK];
  __shared__ __align__(16) u16 sB[2][BN * BK];
  __shared__ float s_gw[BM];

  const int t = threadIdx.x;
  const int wave = t >> 6, lane = t & 63;

  // staging: 2 chunks/plane, chunk i: global row i*64 + t/4, 16B lane slot t&3
  const char *aHi[2], *aLo[2], *bHi[2], *bLo[2];
#pragma unroll
  for (int i = 0; i < 2; ++i) {
    const int m = i * 64 + (t >> 2);
    size_t arow;
    if constexpr (IS_UP) {
      const int gr = r0 + m;
      const int tok = (gr < lim) ? rows[gr] : 0;   // pad rows: safe token 0
      arow = (size_t)tok * DDIM;
    } else {
      arow = (size_t)(r0 + m) * HDIM;
    }
    aHi[i] = (const char*)Ahi + arow * 2 + (t & 3) * 16;
    if constexpr (ALO) aLo[i] = (const char*)Alo + arow * 2 + (t & 3) * 16;
    const size_t brow = ((size_t)e * ND + n0 + m) * KD;
    bHi[i] = (const char*)Bhi + brow * 2 + (t & 3) * 16;
    if constexpr (BLO) bLo[i] = (const char*)Blo + brow * 2 + (t & 3) * 16;
  }
  if constexpr (IS_UP) {
    if (t < BM) { const int gr = r0 + t; s_gw[t] = (gr < lim) ? gw[gr] : 0.f; }
  }

  f32x4 acc[4][4];
#pragma unroll
  for (int a = 0; a < 4; ++a)
#pragma unroll
    for (int b = 0; b < 4; ++b) acc[a][b] = {0.f, 0.f, 0.f, 0.f};

  const int wm0 = (wave >> 1) * 64, wn0 = (wave & 1) * 64;
  const int c16 = lane & 15, grp = lane >> 4;

  for (int kt = 0; kt < KD / BK; ++kt) {
    __syncthreads();
    const size_t kb = (size_t)kt * (BK * 2);
#pragma unroll
    for (int i = 0; i < 2; ++i) {
      gll16(aHi[i] + kb, (char*)&sA[0][0] + i * 4096 + wave * 1024);
      gll16(bHi[i] + kb, (char*)&sB[0][0] + i * 4096 + wave * 1024);
      if constexpr (ALO) gll16(aLo[i] + kb, (char*)&sA[1][0] + i * 4096 + wave * 1024);
      if constexpr (BLO) gll16(bLo[i] + kb, (char*)&sB[1][0] + i * 4096 + wave * 1024);
    }
    __syncthreads();

    bf16x8 fa[4], fb[4], fal[4], fbl[4];
#pragma unroll
    for (int mf = 0; mf < 4; ++mf) {
      const int off = (wm0 + mf * 16 + c16) * BK + grp * 8;   // A: row=lane&15, k=(lane>>4)*8+j
      fa[mf] = *(const bf16x8*)&sA[0][off];
      if constexpr (ALO) fal[mf] = *(const bf16x8*)&sA[1][off];
    }
#pragma unroll
    for (int nf = 0; nf < 4; ++nf) {
      const int off = (wn0 + nf * 16 + c16) * BK + grp * 8;   // B: col=lane&15, k=(lane>>4)*8+j
      fb[nf] = *(const bf16x8*)&sB[0][off];
      if constexpr (BLO) fbl[nf] = *(const bf16x8*)&sB[1][off];
    }
#pragma unroll
    for (int mf = 0; mf < 4; ++mf)
#pragma unroll
      for (int nf = 0; nf < 4; ++nf) {
        acc[mf][nf] = __builtin_amdgcn_mfma_f32_16x16x32_bf16(fa[mf], fb[nf], acc[mf][nf], 0, 0, 0);
        if constexpr (BLO)
          acc[mf][nf] = __builtin_amdgcn_mfma_f32_16x16x32_bf16(fa[mf], fbl[nf], acc[mf][nf], 0, 0, 0);
        if constexpr (ALO)
          acc[mf][nf] = __builtin_amdgcn_mfma_f32_16x16x32_bf16(fal[mf], fb[nf], acc[mf][nf], 0, 0, 0);
      }
  }

#pragma unroll
  for (int mf = 0; mf < 4; ++mf) {
#pragma unroll
    for (int q = 0; q < 4; ++q) {
      const int r = wm0 + mf * 16 + grp * 4 + q;     // C/D: col=lane&15, row=(lane>>4)*4+q (m89)
      const int gr = r0 + r;
      if (gr < lim) {
        if constexpr (IS_UP) {
          const float g = s_gw[r];
#pragma unroll
          for (int nf = 0; nf < 4; ++nf) {
            const int gc = n0 + wn0 + nf * 16 + c16;
            const float v = acc[mf][nf][q];
            const float hg = 0.5f * v * (1.f + erff(v * 0.7071067811865476f)) * g;
            const u16 h = f2bf(hg);
            OHi[(size_t)gr * HDIM + gc] = h;
            if constexpr (WLO) OLo[(size_t)gr * HDIM + gc] = f2bf(hg - bf2f(h));
          }
        } else {
#pragma unroll
          for (int nf = 0; nf < 4; ++nf) {
            const int gc = n0 + wn0 + nf * 16 + c16;
            OF[(size_t)gr * DDIM + gc] = acc[mf][nf][q];
          }
        }
      }
    }
  }
}

// ---------------- combine: y[t] = ydown[pos(t,0)] + ydown[pos(t,1)] ----------------
__global__ __launch_bounds__(256) void k_combine(const float* __restrict__ yd,
                                                 const int* __restrict__ posof,
                                                 float* __restrict__ y) {
  const size_t i = (size_t)blockIdx.x * 256 + threadIdx.x;   // over T*D/4
  const int t = (int)(i >> 8), c = (int)(i & 255);
  const int p0 = posof[t * 2], p1 = posof[t * 2 + 1];
  const float4 a = ((const float4*)yd)[(size_t)p0 * 256 + c];
  const float4 b = ((const float4*)yd)[(size_t)p1 * 256 + c];
  float4 r; r.x = a.x + b.x; r.y = a.y + b.y; r.z = a.z + b.z; r.w = a.w + b.w;
  ((float4*)y)[i] = r;
}

extern "C" void kernel_launch(void* const* d_in, const int* in_sizes, int n_in,
                              void* d_out, int out_size, void* d_ws, size_t ws_size,
                              hipStream_t stream) {
  const float* x  = (const float*)d_in[0];
  const float* Wg = (const float*)d_in[1];
  const float* W1 = (const float*)d_in[2];
  const float* W2 = (const float*)d_in[3];
  float* y = (float*)d_out;
  float* logits = y + (size_t)T_TOK * DDIM;

  char* ws = (char*)d_ws;
  // control block (zeroed each launch)
  int* cnt    = (int*)(ws + 0);
  int* cursor = (int*)(ws + 64);
  int* poff   = (int*)(ws + 128);
  size_t o = 256;
  int*   sel   = (int*)(ws + o);   o += (size_t)R_MAX * 4;
  float* wts   = (float*)(ws + o); o += (size_t)R_MAX * 4;
  int*   posof = (int*)(ws + o);   o += (size_t)R_MAX * 4;
  int*   rows  = (int*)(ws + o);   o += (size_t)R_PAD * 4;
  float* gwp   = (float*)(ws + o); o += (size_t)R_PAD * 4;
  o = (o + 255) & ~(size_t)255;
  const size_t S_XP = (size_t)T_TOK * DDIM * 2;
  const size_t S_WP = (size_t)NEXP * HDIM * DDIM * 2;
  const size_t S_HP = (size_t)R_PAD * HDIM * 2;
  const size_t S_YD = (size_t)R_PAD * DDIM * 4;
  // mandatory region (lvl 0)
  u16* xhi  = (u16*)(ws + o); o += S_XP;
  u16* w1hi = (u16*)(ws + o); o += S_WP;
  u16* w2hi = (u16*)(ws + o); o += S_WP;
  u16* hhi  = (u16*)(ws + o); o += S_HP;
  float* yd = (float*)(ws + o); o += S_YD;
  // lvl 1 extras: split planes for inputs/weights
  u16* xlo  = (u16*)(ws + o); o += S_XP;
  u16* w1lo = (u16*)(ws + o); o += S_WP;
  u16* w2lo = (u16*)(ws + o); o += S_WP;
  const size_t need1 = o;
  // lvl 2 extra: split plane for h
  u16* hlo  = (u16*)(ws + o); o += S_HP;
  const size_t need2 = o;
  const int lvl = (ws_size >= need2) ? 2 : (ws_size >= need1) ? 1 : 0;

  hipMemsetAsync(d_ws, 0, 256, stream);
  k_router<<<T_TOK / 4, 256, 0, stream>>>(x, Wg, logits, sel, wts);
  k_count<<<T_TOK / 256, 256, 0, stream>>>(sel, cnt);
  k_scan<<<1, 64, 0, stream>>>(cnt, poff);
  k_scatter<<<T_TOK / 256, 256, 0, stream>>>(sel, wts, poff, cursor, rows, gwp, posof);
  k_splitx<<<(T_TOK * DDIM / 4) / 256, 256, 0, stream>>>(x, xhi, xlo, lvl >= 1);
  const int tgrid = NEXP * (DDIM / 64) * (HDIM / 64);
  k_tsplit<<<tgrid, 256, 0, stream>>>(W1, w1hi, w1lo, DDIM, HDIM, lvl >= 1);
  k_tsplit<<<tgrid, 256, 0, stream>>>(W2, w2hi, w2lo, HDIM, DDIM, lvl >= 1);

  const int upGrid = ROWTILES * (HDIM / BN);     // 136*32
  const int dnGrid = ROWTILES * (DDIM / BN);     // 136*8
  if (lvl == 2) {
    k_gemm<true,  true,  true,  true ><<<upGrid, 256, 0, stream>>>(xhi, xlo, w1hi, w1lo, poff, cnt, rows, gwp, hhi, hlo, nullptr);
    k_gemm<false, true,  true,  false><<<dnGrid, 256, 0, stream>>>(hhi, hlo, w2hi, w2lo, poff, cnt, rows, gwp, nullptr, nullptr, yd);
  } else if (lvl == 1) {
    k_gemm<true,  true,  true,  false><<<upGrid, 256, 0, stream>>>(xhi, xlo, w1hi, w1lo, poff, cnt, rows, gwp, hhi, nullptr, nullptr);
    k_gemm<false, false, true,  false><<<dnGrid, 256, 0, stream>>>(hhi, nullptr, w2hi, w2lo, poff, cnt, rows, gwp, nullptr, nullptr, yd);
  } else {
    k_gemm<true,  false, false, false><<<upGrid, 256, 0, stream>>>(xhi, nullptr, w1hi, nullptr, poff, cnt, rows, gwp, hhi, nullptr, nullptr);
    k_gemm<false, false, false, false><<<dnGrid, 256, 0, stream>>>(hhi, nullptr, w2hi, nullptr, poff, cnt, rows, gwp, nullptr, nullptr, yd);
  }
  k_combine<<<(T_TOK * DDIM / 4) / 256, 256, 0, stream>>>(yd, posof, y);
}

// Round 5
// 1165.108 us; speedup vs baseline: 1.0202x; 1.0202x over previous
//
#include <hip/hip_runtime.h>
#include <math.h>

// MoE: T=8192 D=1024 H=4096 E=8 top_k=2.
// router -> count -> scan -> scatter -> splitx -> tsplit(W1)
//   -> [up-GEMM + tsplit(W2) fused] -> down-GEMM -> combine.
// GEMMs: split-bf16 (hi/lo) MFMA 16x16x32.
// R3/R4/R5: LDS 2-bit XOR swizzle (source-permuted for gload_lds), exact-size LDS,
//     XCD-chunked block swizzle, W2-transpose fused into up-GEMM, ushort4 tsplit.

#define T_TOK 8192
#define DDIM 1024
#define HDIM 4096
#define NEXP 8
#define BM 128
#define BN 128
#define BK 32
#define R_MAX (T_TOK * 2)
#define R_PAD (R_MAX + NEXP * BM)          // 17408
#define ROWTILES ((R_MAX / BM) + NEXP)     // 136

typedef unsigned short u16;
typedef unsigned int u32;
typedef __attribute__((ext_vector_type(4))) float f32x4;
typedef __attribute__((ext_vector_type(8))) short bf16x8;

__device__ __forceinline__ u16 f2bf(float f) {
  union { float f; u32 u; } v; v.f = f;
  u32 r = v.u + 0x7fffu + ((v.u >> 16) & 1u);   // RNE
  return (u16)(r >> 16);
}
__device__ __forceinline__ float bf2f(u16 h) {
  union { u32 u; float f; } v; v.u = ((u32)h) << 16; return v.f;
}
__device__ __forceinline__ void gll16(const void* g, void* l) {
  __builtin_amdgcn_global_load_lds(
      (const __attribute__((address_space(1))) u32*)g,
      (__attribute__((address_space(3))) u32*)l, 16, 0, 0);
}

// ---------------- router ----------------
__global__ __launch_bounds__(256) void k_router(const float* __restrict__ x,
                                                const float* __restrict__ Wg,
                                                float* __restrict__ logits,
                                                int* __restrict__ sel,
                                                float* __restrict__ wts) {
  __shared__ float wg[NEXP * DDIM];
  const int t = threadIdx.x;
  for (int i = t; i < NEXP * DDIM; i += 256) wg[i] = Wg[i];
  __syncthreads();
  const int wave = t >> 6, lane = t & 63;
  const int tok = blockIdx.x * 4 + wave;
  const float* xr = x + (size_t)tok * DDIM;
  float acc[NEXP];
#pragma unroll
  for (int e = 0; e < NEXP; ++e) acc[e] = 0.f;
  for (int c = 0; c < DDIM / 64; ++c) {
    const float xv = xr[c * 64 + lane];
#pragma unroll
    for (int e = 0; e < NEXP; ++e) acc[e] += xv * wg[e * DDIM + c * 64 + lane];
  }
#pragma unroll
  for (int e = 0; e < NEXP; ++e) {
    float v = acc[e];
    for (int off = 32; off; off >>= 1) v += __shfl_xor(v, off, 64);
    acc[e] = v;
  }
  if (lane < NEXP) logits[(size_t)tok * NEXP + lane] = acc[lane];
  if (lane == 0) {
    int i1 = 0; float m1 = acc[0];
#pragma unroll
    for (int e = 1; e < NEXP; ++e) if (acc[e] > m1) { m1 = acc[e]; i1 = e; }
    int i2 = -1; float m2 = -INFINITY;
#pragma unroll
    for (int e = 0; e < NEXP; ++e) if (e != i1 && acc[e] > m2) { m2 = acc[e]; i2 = e; }
    const float ex = expf(m2 - m1);
    const float w1 = 1.f / (1.f + ex);
    sel[tok * 2 + 0] = i1; sel[tok * 2 + 1] = i2;
    wts[tok * 2 + 0] = w1; wts[tok * 2 + 1] = ex * w1;
  }
}

// ---------------- count ----------------
__global__ __launch_bounds__(256) void k_count(const int* __restrict__ sel, int* __restrict__ cnt) {
  const int t = blockIdx.x * 256 + threadIdx.x;
  const int lane = threadIdx.x & 63;
  for (int k = 0; k < 2; ++k) {
    const int s = sel[t * 2 + k];
#pragma unroll
    for (int e = 0; e < NEXP; ++e) {
      const unsigned long long m = __ballot(s == e);
      if (m && lane == __builtin_ctzll(m)) atomicAdd(&cnt[e], __popcll(m));
    }
  }
}

// ---------------- scan ----------------
__global__ void k_scan(const int* __restrict__ cnt, int* __restrict__ poff) {
  if (threadIdx.x == 0 && blockIdx.x == 0) {
    int run = 0;
    for (int e = 0; e < NEXP; ++e) { poff[e] = run; run += ((cnt[e] + BM - 1) / BM) * BM; }
    poff[NEXP] = run;
  }
}

// ---------------- scatter ----------------
__global__ __launch_bounds__(256) void k_scatter(const int* __restrict__ sel,
                                                 const float* __restrict__ wts,
                                                 const int* __restrict__ poff,
                                                 int* __restrict__ cursor,
                                                 int* __restrict__ rows,
                                                 float* __restrict__ gw,
                                                 int* __restrict__ posof) {
  const int t = blockIdx.x * 256 + threadIdx.x;
  const int lane = threadIdx.x & 63;
  for (int k = 0; k < 2; ++k) {
    const int s = sel[t * 2 + k];
    const float w = wts[t * 2 + k];
#pragma unroll
    for (int e = 0; e < NEXP; ++e) {
      const unsigned long long m = __ballot(s == e);
      if (!m) continue;
      const int leader = __builtin_ctzll(m);
      int base = 0;
      if (lane == leader) base = atomicAdd(&cursor[e], (int)__popcll(m));
      base = __shfl(base, leader, 64);
      if (s == e) {
        const int pos = base + (int)__popcll(m & ((1ull << lane) - 1ull));
        const int g = poff[e] + pos;
        rows[g] = t; gw[g] = w; posof[t * 2 + k] = g;
      }
    }
  }
}

// ---------------- split x ----------------
__global__ __launch_bounds__(256) void k_splitx(const float* __restrict__ x,
                                                u16* __restrict__ xhi, u16* __restrict__ xlo,
                                                int wlo) {
  const size_t i = (size_t)blockIdx.x * 256 + threadIdx.x;
  const float4 v = ((const float4*)x)[i];
  float vv[4] = {v.x, v.y, v.z, v.w};
  u16 h[4], l[4];
#pragma unroll
  for (int j = 0; j < 4; ++j) { h[j] = f2bf(vv[j]); l[j] = f2bf(vv[j] - bf2f(h[j])); }
  ((ushort4*)xhi)[i] = make_ushort4(h[0], h[1], h[2], h[3]);
  if (wlo) ((ushort4*)xlo)[i] = make_ushort4(l[0], l[1], l[2], l[3]);
}

// ---------------- transpose+split body: in [E][Rr][Cc] f32 -> out [E][Cc][Rr] bf16 ----------------
__device__ __forceinline__ void tsplit_body(int bid, char* smemRaw,
                                            const float* __restrict__ in,
                                            u16* __restrict__ ohi, u16* __restrict__ olo,
                                            int Rr, int Cc, int wlo) {
  float (*tile)[65] = (float (*)[65])smemRaw;
  const int tilesC = Cc >> 6;
  const int per = (Rr >> 6) * tilesC;
  const int e = bid / per, rem = bid % per;
  const int rt = rem / tilesC, ct = rem % tilesC;
  const float* bin = in + ((size_t)e * Rr + rt * 64) * Cc + ct * 64;
  const int t = threadIdx.x;
  const int r0 = t >> 6, c = t & 63;
#pragma unroll
  for (int i = 0; i < 16; ++i) tile[i * 4 + r0][c] = bin[(size_t)(i * 4 + r0) * Cc + c];
  __syncthreads();
  u16* bhi = ohi + ((size_t)e * Cc + ct * 64) * Rr + rt * 64;
  u16* blo = olo + ((size_t)e * Cc + ct * 64) * Rr + rt * 64;
#pragma unroll
  for (int j = 0; j < 4; ++j) {
    const int idx = t + j * 256;                 // 0..1023 over 64 rows x 16 chunks
    const int orow = idx >> 4, ch = idx & 15;
    u16 h[4], l[4];
#pragma unroll
    for (int q = 0; q < 4; ++q) {
      const float v = tile[ch * 4 + q][orow];
      h[q] = f2bf(v); l[q] = f2bf(v - bf2f(h[q]));
    }
    *(ushort4*)&bhi[(size_t)orow * Rr + ch * 4] = make_ushort4(h[0], h[1], h[2], h[3]);
    if (wlo) *(ushort4*)&blo[(size_t)orow * Rr + ch * 4] = make_ushort4(l[0], l[1], l[2], l[3]);
  }
}

__global__ __launch_bounds__(256) void k_tsplit(const float* __restrict__ in,
                                                u16* __restrict__ ohi, u16* __restrict__ olo,
                                                int Rr, int Cc, int wlo) {
  __shared__ char smem[64 * 65 * 4];
  tsplit_body(blockIdx.x, smem, in, ohi, olo, Rr, Cc, wlo);
}

// ---------------- grouped GEMM body ----------------
// LDS layout per plane: byte(row, g) = row*64 + (g ^ ((row>>1)&3))*16  (g = 16B granule 0..3)
// gload_lds dest stays linear; the XOR is realized by permuting the per-lane GLOBAL source
// granule: g_src = (t&3) ^ ((t>>3)&3). Frag reads apply the same XOR -> each 16-lane
// quarter-wave covers all 8 bank-quads exactly 2x (2-way = free, m136).
template <bool IS_UP, bool ALO, bool BLO, bool WLO>
__device__ __forceinline__ void gemm_body(int bid0, char* smemRaw,
    const u16* __restrict__ Ahi, const u16* __restrict__ Alo,
    const u16* __restrict__ Bhi, const u16* __restrict__ Blo,
    const int* __restrict__ poff, const int* __restrict__ cnt,
    const int* __restrict__ rows, const float* __restrict__ gw,
    u16* __restrict__ OHi, u16* __restrict__ OLo, float* __restrict__ OF) {
  constexpr int KD = IS_UP ? DDIM : HDIM;
  constexpr int ND = IS_UP ? HDIM : DDIM;
  constexpr int NT = ND / BN;
  constexpr int APL = ALO ? 2 : 1;
  constexpr int BPL = BLO ? 2 : 1;
  constexpr int NWG = ROWTILES * NT;           // divisible by 8
  const int bid = (bid0 & 7) * (NWG >> 3) + (bid0 >> 3);   // XCD-chunked swizzle
  const int rt = bid / NT, ct = bid % NT;
  const int r0 = rt * BM;
  if (r0 >= poff[NEXP]) return;
  int e = 0;
#pragma unroll
  for (int i = 1; i < NEXP; ++i) if (r0 >= poff[i]) e = i;
  const int lim = poff[e] + cnt[e];
  const int n0 = ct * BN;

  u16* sA = (u16*)smemRaw;                              // [APL][BM*BK]
  u16* sB = (u16*)(smemRaw + APL * BM * BK * 2);        // [BPL][BN*BK]
  float* s_gw = (float*)(smemRaw + (APL + BPL) * BM * BK * 2);

  const int t = threadIdx.x;
  const int wave = t >> 6, lane = t & 63;
  const int gsw = (((t & 3) ^ ((t >> 3) & 3)) << 4);    // swizzled source granule byte off

  const char *aHi[2], *aLo[2], *bHi[2], *bLo[2];
#pragma unroll
  for (int i = 0; i < 2; ++i) {
    const int m = i * 64 + (t >> 2);
    size_t arow;
    if constexpr (IS_UP) {
      const int gr = r0 + m;
      const int tok = (gr < lim) ? rows[gr] : 0;
      arow = (size_t)tok * DDIM;
    } else {
      arow = (size_t)(r0 + m) * HDIM;
    }
    aHi[i] = (const char*)Ahi + arow * 2 + gsw;
    if constexpr (ALO) aLo[i] = (const char*)Alo + arow * 2 + gsw;
    const size_t brow = ((size_t)e * ND + n0 + m) * KD;
    bHi[i] = (const char*)Bhi + brow * 2 + gsw;
    if constexpr (BLO) bLo[i] = (const char*)Blo + brow * 2 + gsw;
  }
  if constexpr (IS_UP) {
    if (t < BM) { const int gr = r0 + t; s_gw[t] = (gr < lim) ? gw[gr] : 0.f; }
  }

  f32x4 acc[4][4];
#pragma unroll
  for (int a = 0; a < 4; ++a)
#pragma unroll
    for (int b = 0; b < 4; ++b) acc[a][b] = {0.f, 0.f, 0.f, 0.f};

  const int wm0 = (wave >> 1) * 64, wn0 = (wave & 1) * 64;
  const int c16 = lane & 15, grp = lane >> 4;
  const int gsr = (grp ^ ((c16 >> 1) & 3)) << 3;        // swizzled read granule (u16 units)

  for (int kt = 0; kt < KD / BK; ++kt) {
    __syncthreads();
    const size_t kb = (size_t)kt * (BK * 2);
#pragma unroll
    for (int i = 0; i < 2; ++i) {
      gll16(aHi[i] + kb, (char*)sA + i * 4096 + wave * 1024);
      gll16(bHi[i] + kb, (char*)sB + i * 4096 + wave * 1024);
      if constexpr (ALO) gll16(aLo[i] + kb, (char*)sA + 8192 + i * 4096 + wave * 1024);
      if constexpr (BLO) gll16(bLo[i] + kb, (char*)sB + 8192 + i * 4096 + wave * 1024);
    }
    __syncthreads();

    bf16x8 fa[4], fb[4], fal[4], fbl[4];
#pragma unroll
    for (int mf = 0; mf < 4; ++mf) {
      const int off = (wm0 + mf * 16 + c16) * BK + gsr;
      fa[mf] = *(const bf16x8*)&sA[off];
      if constexpr (ALO) fal[mf] = *(const bf16x8*)&sA[BM * BK + off];
    }
#pragma unroll
    for (int nf = 0; nf < 4; ++nf) {
      const int off = (wn0 + nf * 16 + c16) * BK + gsr;
      fb[nf] = *(const bf16x8*)&sB[off];
      if constexpr (BLO) fbl[nf] = *(const bf16x8*)&sB[BN * BK + off];
    }
#pragma unroll
    for (int mf = 0; mf < 4; ++mf)
#pragma unroll
      for (int nf = 0; nf < 4; ++nf) {
        acc[mf][nf] = __builtin_amdgcn_mfma_f32_16x16x32_bf16(fa[mf], fb[nf], acc[mf][nf], 0, 0, 0);
        if constexpr (BLO)
          acc[mf][nf] = __builtin_amdgcn_mfma_f32_16x16x32_bf16(fa[mf], fbl[nf], acc[mf][nf], 0, 0, 0);
        if constexpr (ALO)
          acc[mf][nf] = __builtin_amdgcn_mfma_f32_16x16x32_bf16(fal[mf], fb[nf], acc[mf][nf], 0, 0, 0);
      }
  }

#pragma unroll
  for (int mf = 0; mf < 4; ++mf) {
#pragma unroll
    for (int q = 0; q < 4; ++q) {
      const int r = wm0 + mf * 16 + grp * 4 + q;     // C/D: col=lane&15, row=(lane>>4)*4+q
      const int gr = r0 + r;
      if (gr < lim) {
        if constexpr (IS_UP) {
          const float g = s_gw[r];
#pragma unroll
          for (int nf = 0; nf < 4; ++nf) {
            const int gc = n0 + wn0 + nf * 16 + c16;
            const float v = acc[mf][nf][q];
            const float hg = 0.5f * v * (1.f + erff(v * 0.7071067811865476f)) * g;
            const u16 h = f2bf(hg);
            OHi[(size_t)gr * HDIM + gc] = h;
            if constexpr (WLO) OLo[(size_t)gr * HDIM + gc] = f2bf(hg - bf2f(h));
          }
        } else {
#pragma unroll
          for (int nf = 0; nf < 4; ++nf) {
            const int gc = n0 + wn0 + nf * 16 + c16;
            OF[(size_t)gr * DDIM + gc] = acc[mf][nf][q];
          }
        }
      }
    }
  }
}

// standalone down-GEMM
template <bool ALO, bool BLO>
__global__ __launch_bounds__(256, 2) void k_gemm_dn(
    const u16* __restrict__ Ahi, const u16* __restrict__ Alo,
    const u16* __restrict__ Bhi, const u16* __restrict__ Blo,
    const int* __restrict__ poff, const int* __restrict__ cnt,
    float* __restrict__ OF) {
  constexpr int SZ = ((ALO ? 2 : 1) + (BLO ? 2 : 1)) * BM * BK * 2 + 16;
  __shared__ __align__(16) char smem[SZ];
  gemm_body<false, ALO, BLO, false>(blockIdx.x, smem, Ahi, Alo, Bhi, Blo,
                                    poff, cnt, nullptr, nullptr, nullptr, nullptr, OF);
}

// fused: up-GEMM blocks then tsplit(W2) blocks
#define UPGRID (ROWTILES * (HDIM / BN))      // 4352
template <bool ALO, bool BLO, bool WLO>
__global__ __launch_bounds__(256, 2) void k_up_fused(
    const u16* __restrict__ Ahi, const u16* __restrict__ Alo,
    const u16* __restrict__ Bhi, const u16* __restrict__ Blo,
    const int* __restrict__ poff, const int* __restrict__ cnt,
    const int* __restrict__ rows, const float* __restrict__ gw,
    u16* __restrict__ OHi, u16* __restrict__ OLo,
    const float* __restrict__ W2, u16* __restrict__ w2hi, u16* __restrict__ w2lo, int wlo) {
  constexpr int GSZ = ((ALO ? 2 : 1) + (BLO ? 2 : 1)) * BM * BK * 2 + BM * 4;
  constexpr int SZ = GSZ > (64 * 65 * 4) ? GSZ : (64 * 65 * 4);
  __shared__ __align__(16) char smem[SZ];
  if (blockIdx.x < UPGRID)
    gemm_body<true, ALO, BLO, WLO>(blockIdx.x, smem, Ahi, Alo, Bhi, Blo,
                                   poff, cnt, rows, gw, OHi, OLo, nullptr);
  else
    tsplit_body(blockIdx.x - UPGRID, smem, W2, w2hi, w2lo, HDIM, DDIM, wlo);
}

// ---------------- combine ----------------
__global__ __launch_bounds__(256) void k_combine(const float* __restrict__ yd,
                                                 const int* __restrict__ posof,
                                                 float* __restrict__ y) {
  const size_t i = (size_t)blockIdx.x * 256 + threadIdx.x;
  const int t = (int)(i >> 8), c = (int)(i & 255);
  const int p0 = posof[t * 2], p1 = posof[t * 2 + 1];
  const float4 a = ((const float4*)yd)[(size_t)p0 * 256 + c];
  const float4 b = ((const float4*)yd)[(size_t)p1 * 256 + c];
  float4 r; r.x = a.x + b.x; r.y = a.y + b.y; r.z = a.z + b.z; r.w = a.w + b.w;
  ((float4*)y)[i] = r;
}

extern "C" void kernel_launch(void* const* d_in, const int* in_sizes, int n_in,
                              void* d_out, int out_size, void* d_ws, size_t ws_size,
                              hipStream_t stream) {
  const float* x  = (const float*)d_in[0];
  const float* Wg = (const float*)d_in[1];
  const float* W1 = (const float*)d_in[2];
  const float* W2 = (const float*)d_in[3];
  float* y = (float*)d_out;
  float* logits = y + (size_t)T_TOK * DDIM;

  char* ws = (char*)d_ws;
  int* cnt    = (int*)(ws + 0);
  int* cursor = (int*)(ws + 64);
  int* poff   = (int*)(ws + 128);
  size_t o = 256;
  int*   sel   = (int*)(ws + o);   o += (size_t)R_MAX * 4;
  float* wts   = (float*)(ws + o); o += (size_t)R_MAX * 4;
  int*   posof = (int*)(ws + o);   o += (size_t)R_MAX * 4;
  int*   rows  = (int*)(ws + o);   o += (size_t)R_PAD * 4;
  float* gwp   = (float*)(ws + o); o += (size_t)R_PAD * 4;
  o = (o + 255) & ~(size_t)255;
  const size_t S_XP = (size_t)T_TOK * DDIM * 2;
  const size_t S_WP = (size_t)NEXP * HDIM * DDIM * 2;
  const size_t S_HP = (size_t)R_PAD * HDIM * 2;
  const size_t S_YD = (size_t)R_PAD * DDIM * 4;
  // mandatory (lvl 0)
  u16* xhi  = (u16*)(ws + o); o += S_XP;
  u16* w1hi = (u16*)(ws + o); o += S_WP;
  u16* w2hi = (u16*)(ws + o); o += S_WP;
  u16* hhi  = (u16*)(ws + o); o += S_HP;
  float* yd = (float*)(ws + o); o += S_YD;
  // lvl 1 extras
  u16* xlo  = (u16*)(ws + o); o += S_XP;
  u16* w1lo = (u16*)(ws + o); o += S_WP;
  u16* w2lo = (u16*)(ws + o); o += S_WP;
  const size_t need1 = o;
  // lvl 2 extra
  u16* hlo  = (u16*)(ws + o); o += S_HP;
  const size_t need2 = o;
  const int lvl = (ws_size >= need2) ? 2 : (ws_size >= need1) ? 1 : 0;

  hipMemsetAsync(d_ws, 0, 256, stream);
  k_router<<<T_TOK / 4, 256, 0, stream>>>(x, Wg, logits, sel, wts);
  k_count<<<T_TOK / 256, 256, 0, stream>>>(sel, cnt);
  k_scan<<<1, 64, 0, stream>>>(cnt, poff);
  k_scatter<<<T_TOK / 256, 256, 0, stream>>>(sel, wts, poff, cursor, rows, gwp, posof);
  k_splitx<<<(T_TOK * DDIM / 4) / 256, 256, 0, stream>>>(x, xhi, xlo, lvl >= 1);
  const int tgrid = NEXP * (DDIM / 64) * (HDIM / 64);   // 8192
  k_tsplit<<<tgrid, 256, 0, stream>>>(W1, w1hi, w1lo, DDIM, HDIM, lvl >= 1);

  const int fusedGrid = UPGRID + tgrid;                 // 4352 + 8192
  const int dnGrid = ROWTILES * (DDIM / BN);            // 1088
  if (lvl == 2) {
    k_up_fused<true, true, true><<<fusedGrid, 256, 0, stream>>>(
        xhi, xlo, w1hi, w1lo, poff, cnt, rows, gwp, hhi, hlo, W2, w2hi, w2lo, 1);
    k_gemm_dn<true, true><<<dnGrid, 256, 0, stream>>>(hhi, hlo, w2hi, w2lo, poff, cnt, yd);
  } else if (lvl == 1) {
    k_up_fused<true, true, false><<<fusedGrid, 256, 0, stream>>>(
        xhi, xlo, w1hi, w1lo, poff, cnt, rows, gwp, hhi, nullptr, W2, w2hi, w2lo, 1);
    k_gemm_dn<false, true><<<dnGrid, 256, 0, stream>>>(hhi, nullptr, w2hi, w2lo, poff, cnt, yd);
  } else {
    k_up_fused<false, false, false><<<fusedGrid, 256, 0, stream>>>(
        xhi, nullptr, w1hi, nullptr, poff, cnt, rows, gwp, hhi, nullptr, W2, w2hi, w2lo, 0);
    k_gemm_dn<false, false><<<dnGrid, 256, 0, stream>>>(hhi, nullptr, w2hi, nullptr, poff, cnt, yd);
  }
  k_combine<<<(T_TOK * DDIM / 4) / 256, 256, 0, stream>>>(yd, posof, y);
}